// Round 1
// baseline (228.185 us; speedup 1.0000x reference)
//
#include <hip/hip_runtime.h>

#define NB 8
#define NC 2048
#define KIN 128
#define NF 64

#define WTSTRIDE 136          // k1 LDS W^T row stride (ushorts)
#define RSTRIDE 68            // k2 reduce row stride (floats)
#define MOFF 60.0f            // log2-domain slack: p <= 2^60, f32 sum < 2^71
#define LOG2E 1.4426950408889634f

typedef float floatx4_t __attribute__((ext_vector_type(4)));
typedef __bf16 bf16x8_t __attribute__((ext_vector_type(8)));
typedef unsigned short ushort8_t __attribute__((ext_vector_type(8)));

static __device__ __forceinline__ unsigned short f2bf(float f) {
  union { float f; unsigned int u; } v; v.f = f;
  unsigned int u = v.u;
  u += 0x7FFFu + ((u >> 16) & 1u);   // RNE; inputs never NaN
  return (unsigned short)(u >> 16);
}

// ---------------------------------------------------------------------------
// Kernel 1 (UNCHANGED from 227us baseline): per block = 64 rows of one batch.
//   - w1 = W@a1, w2 = W@a2; s1/s2 fp32-exact via H@(W@a) (4 threads per row)
//   - WhT[b,f,c] = bf16((H@W)^T) via MFMA: D = W^T (f x k) * H^T (k x c)
// ---------------------------------------------------------------------------
__global__ __launch_bounds__(256, 2) void k1_prep(
    const float* __restrict__ H, const float* __restrict__ W,
    const float* __restrict__ avec,
    float* __restrict__ s1g, float* __restrict__ s2g,
    unsigned short* __restrict__ WhT)
{
  __shared__ unsigned short WTsh[NF * WTSTRIDE];   // 17.4 KB
  __shared__ float w1sh[KIN];
  __shared__ float w2sh[KIN];

  const int t = threadIdx.x;
  const int b = blockIdx.x >> 5;
  const int c0 = (blockIdx.x & 31) * 64;

  for (int i = t; i < KIN * NF; i += 256) {
    int k = i >> 6, f = i & 63;
    WTsh[f * WTSTRIDE + k] = f2bf(W[i]);
  }
  if (t < KIN) {
    float acc1 = 0.f, acc2 = 0.f;
    const float* wr = W + t * NF;
#pragma unroll
    for (int f = 0; f < NF; ++f) {
      float wv = wr[f];
      acc1 += wv * avec[f];
      acc2 += wv * avec[NF + f];
    }
    w1sh[t] = acc1;
    w2sh[t] = acc2;
  }
  __syncthreads();

  {
    const int r = t >> 2;          // 0..63
    const int qq = t & 3;
    const float* hp = H + (size_t)(b * NC + c0 + r) * KIN + qq * 32;
    const float* w1p = w1sh + qq * 32;
    const float* w2p = w2sh + qq * 32;
    float p1 = 0.f, p2 = 0.f;
#pragma unroll
    for (int j = 0; j < 8; ++j) {
      float4 h = *(const float4*)(hp + j * 4);
      float4 u1 = *(const float4*)(w1p + j * 4);
      float4 u2 = *(const float4*)(w2p + j * 4);
      p1 += h.x * u1.x + h.y * u1.y + h.z * u1.z + h.w * u1.w;
      p2 += h.x * u2.x + h.y * u2.y + h.z * u2.z + h.w * u2.w;
    }
    p1 += __shfl_xor(p1, 1); p2 += __shfl_xor(p2, 1);
    p1 += __shfl_xor(p1, 2); p2 += __shfl_xor(p2, 2);
    if (qq == 0) {
      s1g[b * NC + c0 + r] = p1;
      s2g[b * NC + c0 + r] = p2;
    }
  }

  const int wave = t >> 6;
  const int lane = t & 63;
  const int m = lane & 15;
  const int q = lane >> 4;
  floatx4_t acc[4];
#pragma unroll
  for (int mt = 0; mt < 4; ++mt) acc[mt] = (floatx4_t){0.f, 0.f, 0.f, 0.f};

  const float* hb = H + (size_t)(b * NC + c0 + wave * 16 + m) * KIN;
#pragma unroll
  for (int kt = 0; kt < 4; ++kt) {
    const int kbase = kt * 32 + q * 8;
    float4 h0 = *(const float4*)(hb + kbase);
    float4 h1 = *(const float4*)(hb + kbase + 4);
    ushort8_t bu;
    bu[0] = f2bf(h0.x); bu[1] = f2bf(h0.y); bu[2] = f2bf(h0.z); bu[3] = f2bf(h0.w);
    bu[4] = f2bf(h1.x); bu[5] = f2bf(h1.y); bu[6] = f2bf(h1.z); bu[7] = f2bf(h1.w);
    bf16x8_t bf = __builtin_bit_cast(bf16x8_t, bu);
#pragma unroll
    for (int mt = 0; mt < 4; ++mt) {
      ushort8_t au = *(const ushort8_t*)(WTsh + (mt * 16 + m) * WTSTRIDE + kbase);
      bf16x8_t af = __builtin_bit_cast(bf16x8_t, au);
      acc[mt] = __builtin_amdgcn_mfma_f32_16x16x32_bf16(af, bf, acc[mt], 0, 0, 0);
    }
  }
#pragma unroll
  for (int mt = 0; mt < 4; ++mt) {
#pragma unroll
    for (int i2 = 0; i2 < 4; ++i2) {
      const int f = mt * 16 + q * 4 + i2;
      WhT[(size_t)(b * NF + f) * NC + c0 + wave * 16 + m] = f2bf(acc[mt][i2]);
    }
  }
}

// ---------------------------------------------------------------------------
// Kernel 2 v2: per block = 16 query rows. Changes vs baseline:
//   * __launch_bounds__(256,4): VGPR<=128 -> 4 blocks/CU (2x occupancy)
//   * A prefetched 2 K-tiles ahead (named regs, unroll-by-2)
//   * exp2-domain softmax (s1/s2 pre-scaled by log2e at staging); mm folded
//     into sub/fma -> add,sub,fma,max,v_exp per element
//   * native (__bf16) casts -> v_cvt_pk_bf16_f32 packing
//   * diagonal test hoisted to the single block-uniform K-tile kdiag = i0>>5
// ---------------------------------------------------------------------------
__global__ __launch_bounds__(256, 4) void k2_attn(
    const int* __restrict__ A, const float* __restrict__ s1g,
    const float* __restrict__ s2g, const unsigned short* __restrict__ WhT,
    float* __restrict__ out)
{
  __shared__ float s2_sh[NC];                   // 8 KB (log2e-scaled)
  __shared__ float s1_sh[16];
  __shared__ float wmax_sh[4];
  __shared__ float red_sh[4 * 16 * RSTRIDE];    // 17.4 KB
  __shared__ float lsum_sh[4 * 16];

  const int t = threadIdx.x;
  const int b = blockIdx.x >> 7;
  const int i0 = (blockIdx.x & 127) * 16;
  const int wave = t >> 6;
  const int lane = t & 63;

  // stage s2 * log2e (two coalesced float4 sweeps) + batch-max (scaled domain)
  float lmax;
  {
    const float* sp = s2g + b * NC;
    float4 v0 = *(const float4*)(sp + t * 4);
    float4 v1 = *(const float4*)(sp + 1024 + t * 4);
    v0.x *= LOG2E; v0.y *= LOG2E; v0.z *= LOG2E; v0.w *= LOG2E;
    v1.x *= LOG2E; v1.y *= LOG2E; v1.z *= LOG2E; v1.w *= LOG2E;
    *(float4*)(s2_sh + t * 4) = v0;
    *(float4*)(s2_sh + 1024 + t * 4) = v1;
    lmax = fmaxf(fmaxf(fmaxf(v0.x, v0.y), fmaxf(v0.z, v0.w)),
                 fmaxf(fmaxf(v1.x, v1.y), fmaxf(v1.z, v1.w)));
#pragma unroll
    for (int off = 1; off < 64; off <<= 1)
      lmax = fmaxf(lmax, __shfl_xor(lmax, off));
    if (lane == 0) wmax_sh[wave] = lmax;
  }
  if (t < 16) s1_sh[t] = s1g[b * NC + i0 + t] * LOG2E;
  __syncthreads();

  const float s2max =
      fmaxf(fmaxf(wmax_sh[0], wmax_sh[1]), fmaxf(wmax_sh[2], wmax_sh[3]));

  const int m = lane & 15;   // A-frag row (query sub) and B-frag col (f sub)
  const int q = lane >> 4;
  const int gi = i0 + m;
  const float s1m = s1_sh[m];
  // upper bound of lrelu(s1m+s2j) in log2 domain, minus slack
  const float mm = fmaxf(s1m + s2max, 0.2f * (s1m + s2max)) - MOFF;
  const int* Ap = A + ((size_t)b * NC + gi) * NC;
  const unsigned short* whb = WhT + (size_t)b * NF * NC;

  // ones B-fragment: column 0 of tile = 1.0 -> accl col0 = row sums of P
  bf16x8_t onesf;
  {
    const __bf16 ov = (__bf16)((m == 0) ? 1.0f : 0.0f);
#pragma unroll
    for (int idx = 0; idx < 8; ++idx) onesf[idx] = ov;
  }

  floatx4_t acc[4], accl;
#pragma unroll
  for (int nt = 0; nt < 4; ++nt) acc[nt] = (floatx4_t){0.f, 0.f, 0.f, 0.f};
  accl = (floatx4_t){0.f, 0.f, 0.f, 0.f};

  // diagonal lives in the single K-tile kdiag for ALL 16 rows of this block
  // (i0 % 16 == 0 -> the 16-row window never crosses a 32-col boundary)
  const int kdiag = i0 >> 5;
  const int ktBeg = wave * 16, ktEnd = ktBeg + 16;
  const int* apb = Ap + q * 8;

#define BODY(KT, A0, A1)                                                      \
  {                                                                           \
    const int jq = (KT) * 32 + q * 8;                                         \
    ushort8_t bu0 = *(const ushort8_t*)(whb + (size_t)(0 * 16 + m) * NC + jq);\
    ushort8_t bu1 = *(const ushort8_t*)(whb + (size_t)(1 * 16 + m) * NC + jq);\
    ushort8_t bu2 = *(const ushort8_t*)(whb + (size_t)(2 * 16 + m) * NC + jq);\
    ushort8_t bu3 = *(const ushort8_t*)(whb + (size_t)(3 * 16 + m) * NC + jq);\
    float4 sA = *(const float4*)(s2_sh + jq);                                 \
    float4 sB = *(const float4*)(s2_sh + jq + 4);                             \
    const float sv[8] = {sA.x, sA.y, sA.z, sA.w, sB.x, sB.y, sB.z, sB.w};     \
    const int av[8] = {(A0).x, (A0).y, (A0).z, (A0).w,                        \
                       (A1).x, (A1).y, (A1).z, (A1).w};                       \
    float pm[8];                                                              \
    _Pragma("unroll")                                                         \
    for (int idx = 0; idx < 8; ++idx) {                                       \
      float x = s1m + sv[idx];                                                \
      float l = fmaxf(x - mm, __builtin_fmaf(0.2f, x, -mm));                  \
      pm[idx] = __builtin_amdgcn_exp2f(l);                                    \
    }                                                                         \
    if ((KT) == kdiag) {                                                      \
      _Pragma("unroll")                                                       \
      for (int idx = 0; idx < 8; ++idx)                                       \
        pm[idx] = ((av[idx] > 0) | (jq + idx == gi)) ? pm[idx] : 0.f;         \
    } else {                                                                  \
      _Pragma("unroll")                                                       \
      for (int idx = 0; idx < 8; ++idx)                                       \
        pm[idx] = (av[idx] > 0) ? pm[idx] : 0.f;                              \
    }                                                                         \
    bf16x8_t af;                                                              \
    _Pragma("unroll")                                                         \
    for (int idx = 0; idx < 8; ++idx) af[idx] = (__bf16)pm[idx];              \
    acc[0] = __builtin_amdgcn_mfma_f32_16x16x32_bf16(                         \
        af, __builtin_bit_cast(bf16x8_t, bu0), acc[0], 0, 0, 0);              \
    acc[1] = __builtin_amdgcn_mfma_f32_16x16x32_bf16(                         \
        af, __builtin_bit_cast(bf16x8_t, bu1), acc[1], 0, 0, 0);              \
    acc[2] = __builtin_amdgcn_mfma_f32_16x16x32_bf16(                         \
        af, __builtin_bit_cast(bf16x8_t, bu2), acc[2], 0, 0, 0);              \
    acc[3] = __builtin_amdgcn_mfma_f32_16x16x32_bf16(                         \
        af, __builtin_bit_cast(bf16x8_t, bu3), acc[3], 0, 0, 0);              \
    accl = __builtin_amdgcn_mfma_f32_16x16x32_bf16(af, onesf, accl, 0, 0, 0); \
  }

  // depth-2 A prefetch, unroll-by-2 with named register sets (no dyn indexing)
  int4 aA0 = *(const int4*)(apb + ktBeg * 32);
  int4 aA1 = *(const int4*)(apb + ktBeg * 32 + 4);
  int4 aB0 = *(const int4*)(apb + (ktBeg + 1) * 32);
  int4 aB1 = *(const int4*)(apb + (ktBeg + 1) * 32 + 4);

  for (int kt = ktBeg; kt < ktEnd; kt += 2) {
    {
      const int4 c0 = aA0, c1 = aA1;
      const int ktp = (kt + 2 < ktEnd) ? kt + 2 : ktEnd - 1;  // clamp: safe
      aA0 = *(const int4*)(apb + ktp * 32);
      aA1 = *(const int4*)(apb + ktp * 32 + 4);
      BODY(kt, c0, c1);
    }
    {
      const int4 c0 = aB0, c1 = aB1;
      const int ktp = (kt + 3 < ktEnd) ? kt + 3 : ktEnd - 1;  // clamp: safe
      aB0 = *(const int4*)(apb + ktp * 32);
      aB1 = *(const int4*)(apb + ktp * 32 + 4);
      BODY(kt + 1, c0, c1);
    }
  }
#undef BODY

  // cross-wave reduce: acc D[row=q*4+i2][col=m(+nt*16)], lsum from accl col 0
#pragma unroll
  for (int nt = 0; nt < 4; ++nt) {
#pragma unroll
    for (int i2 = 0; i2 < 4; ++i2) {
      red_sh[wave * (16 * RSTRIDE) + (q * 4 + i2) * RSTRIDE + nt * 16 + m] =
          acc[nt][i2];
    }
  }
  if (m == 0) {
#pragma unroll
    for (int i2 = 0; i2 < 4; ++i2)
      lsum_sh[wave * 16 + q * 4 + i2] = accl[i2];
  }
  __syncthreads();

  {
    const int row = t >> 4;
    const int f0 = (t & 15) * 4;
    float4 v = {0.f, 0.f, 0.f, 0.f};
    float ls = 0.f;
#pragma unroll
    for (int w = 0; w < 4; ++w) {
      const float* rp = red_sh + w * (16 * RSTRIDE) + row * RSTRIDE + f0;
      float4 vv = *(const float4*)rp;
      v.x += vv.x; v.y += vv.y; v.z += vv.z; v.w += vv.w;
      ls += lsum_sh[w * 16 + row];
    }
    const float inv = 1.0f / ls;
    float4 o;
    o.x = fmaxf(v.x * inv, 0.f);
    o.y = fmaxf(v.y * inv, 0.f);
    o.z = fmaxf(v.z * inv, 0.f);
    o.w = fmaxf(v.w * inv, 0.f);
    *(float4*)(out + (size_t)(b * NC + i0 + row) * NF + f0) = o;
  }
}

extern "C" void kernel_launch(void* const* d_in, const int* in_sizes, int n_in,
                              void* d_out, int out_size, void* d_ws, size_t ws_size,
                              hipStream_t stream) {
  const float* H = (const float*)d_in[0];
  const int* A = (const int*)d_in[1];
  const float* W = (const float*)d_in[2];
  const float* avec = (const float*)d_in[3];
  float* out = (float*)d_out;

  char* ws = (char*)d_ws;
  unsigned short* WhT = (unsigned short*)ws;                    // 2 MB
  float* s1 = (float*)(ws + (size_t)NB * NF * NC * 2);          // 64 KB
  float* s2 = s1 + NB * NC;                                     // 64 KB

  k1_prep<<<dim3(NB * (NC / 64)), dim3(256), 0, stream>>>(H, W, avec, s1, s2, WhT);
  k2_attn<<<dim3(NB * (NC / 16)), dim3(256), 0, stream>>>(A, s1, s2, WhT, out);
}

// Round 2
// 226.737 us; speedup vs baseline: 1.0064x; 1.0064x over previous
//
#include <hip/hip_runtime.h>

#define NB 8
#define NC 2048
#define KIN 128
#define NF 64

#define WTSTRIDE 136          // k1 LDS W^T row stride (ushorts)
#define RSTRIDE 68            // k2 reduce row stride (floats)
#define MOFF 60.0f            // log2-domain slack: p <= 2^60, f32 sum < 2^71
#define LOG2E 1.4426950408889634f

typedef float floatx4_t __attribute__((ext_vector_type(4)));
typedef __bf16 bf16x8_t __attribute__((ext_vector_type(8)));
typedef unsigned short ushort8_t __attribute__((ext_vector_type(8)));

static __device__ __forceinline__ unsigned short f2bf(float f) {
  union { float f; unsigned int u; } v; v.f = f;
  unsigned int u = v.u;
  u += 0x7FFFu + ((u >> 16) & 1u);   // RNE; inputs never NaN
  return (unsigned short)(u >> 16);
}

// ---------------------------------------------------------------------------
// Kernel 1 v3: per block = 64 rows of one batch. Single pass over H:
// s1/s2 partial dots are fused into the MFMA k-loop (H read ONCE, was twice).
//   - w1 = W@a1, w2 = W@a2 in LDS; s1/s2 fp32-exact via H@(W@a)
//   - WhT[b,f,c] = bf16((H@W)^T) via MFMA: D = W^T (f x k) * H^T (k x c)
//   - per row, the 4 lanes q=0..3 cover k in {kt*32+q*8..+8 | kt=0..3};
//     p1/p2 reduced via shfl_xor(16/32) across the q-groups.
// ---------------------------------------------------------------------------
__global__ __launch_bounds__(256, 2) void k1_prep(
    const float* __restrict__ H, const float* __restrict__ W,
    const float* __restrict__ avec,
    float* __restrict__ s1g, float* __restrict__ s2g,
    unsigned short* __restrict__ WhT)
{
  __shared__ unsigned short WTsh[NF * WTSTRIDE];   // 17.4 KB
  __shared__ float w1sh[KIN];
  __shared__ float w2sh[KIN];

  const int t = threadIdx.x;
  const int b = blockIdx.x >> 5;
  const int c0 = (blockIdx.x & 31) * 64;

  // build bf16 W^T in LDS (coalesced global read)
  for (int i = t; i < KIN * NF; i += 256) {
    int k = i >> 6, f = i & 63;
    WTsh[f * WTSTRIDE + k] = f2bf(W[i]);
  }
  // w1/w2 (fp32 exact)
  if (t < KIN) {
    float acc1 = 0.f, acc2 = 0.f;
    const float* wr = W + t * NF;
#pragma unroll
    for (int f = 0; f < NF; ++f) {
      float wv = wr[f];
      acc1 += wv * avec[f];
      acc2 += wv * avec[NF + f];
    }
    w1sh[t] = acc1;
    w2sh[t] = acc2;
  }
  __syncthreads();

  const int wave = t >> 6;
  const int lane = t & 63;
  const int m = lane & 15;   // A-row (f sub) and B-col (c sub)
  const int q = lane >> 4;
  floatx4_t acc[4];
#pragma unroll
  for (int mt = 0; mt < 4; ++mt) acc[mt] = (floatx4_t){0.f, 0.f, 0.f, 0.f};

  const int row = c0 + wave * 16 + m;
  const float* hb = H + (size_t)(b * NC + row) * KIN;
  float p1 = 0.f, p2 = 0.f;

#pragma unroll
  for (int kt = 0; kt < 4; ++kt) {
    const int kbase = kt * 32 + q * 8;
    float4 h0 = *(const float4*)(hb + kbase);
    float4 h1 = *(const float4*)(hb + kbase + 4);

    // fused s1/s2 partials from the same fp32 values (pre-bf16)
    const float* w1p = w1sh + kbase;
    const float* w2p = w2sh + kbase;
    p1 += h0.x * w1p[0] + h0.y * w1p[1] + h0.z * w1p[2] + h0.w * w1p[3]
        + h1.x * w1p[4] + h1.y * w1p[5] + h1.z * w1p[6] + h1.w * w1p[7];
    p2 += h0.x * w2p[0] + h0.y * w2p[1] + h0.z * w2p[2] + h0.w * w2p[3]
        + h1.x * w2p[4] + h1.y * w2p[5] + h1.z * w2p[6] + h1.w * w2p[7];

    ushort8_t bu;
    bu[0] = f2bf(h0.x); bu[1] = f2bf(h0.y); bu[2] = f2bf(h0.z); bu[3] = f2bf(h0.w);
    bu[4] = f2bf(h1.x); bu[5] = f2bf(h1.y); bu[6] = f2bf(h1.z); bu[7] = f2bf(h1.w);
    bf16x8_t bf = __builtin_bit_cast(bf16x8_t, bu);
#pragma unroll
    for (int mt = 0; mt < 4; ++mt) {
      ushort8_t au = *(const ushort8_t*)(WTsh + (mt * 16 + m) * WTSTRIDE + kbase);
      bf16x8_t af = __builtin_bit_cast(bf16x8_t, au);
      acc[mt] = __builtin_amdgcn_mfma_f32_16x16x32_bf16(af, bf, acc[mt], 0, 0, 0);
    }
  }

  // reduce s1/s2 partials across the 4 q-groups of this row
  p1 += __shfl_xor(p1, 16); p2 += __shfl_xor(p2, 16);
  p1 += __shfl_xor(p1, 32); p2 += __shfl_xor(p2, 32);
  if (q == 0) {
    s1g[b * NC + row] = p1;
    s2g[b * NC + row] = p2;
  }

  // D[row = q*4+i2 -> f][col = m -> c]
#pragma unroll
  for (int mt = 0; mt < 4; ++mt) {
#pragma unroll
    for (int i2 = 0; i2 < 4; ++i2) {
      const int f = mt * 16 + q * 4 + i2;
      WhT[(size_t)(b * NF + f) * NC + c0 + wave * 16 + m] = f2bf(acc[mt][i2]);
    }
  }
}

// ---------------------------------------------------------------------------
// Kernel 2 (unchanged v2): per block = 16 query rows; A-BW-bound (~134 MB
// compulsory). exp2-domain softmax, depth-2 A prefetch, hoisted diagonal,
// native bf16 packing, __launch_bounds__(256,4).
// ---------------------------------------------------------------------------
__global__ __launch_bounds__(256, 4) void k2_attn(
    const int* __restrict__ A, const float* __restrict__ s1g,
    const float* __restrict__ s2g, const unsigned short* __restrict__ WhT,
    float* __restrict__ out)
{
  __shared__ float s2_sh[NC];                   // 8 KB (log2e-scaled)
  __shared__ float s1_sh[16];
  __shared__ float wmax_sh[4];
  __shared__ float red_sh[4 * 16 * RSTRIDE];    // 17.4 KB
  __shared__ float lsum_sh[4 * 16];

  const int t = threadIdx.x;
  const int b = blockIdx.x >> 7;
  const int i0 = (blockIdx.x & 127) * 16;
  const int wave = t >> 6;
  const int lane = t & 63;

  // stage s2 * log2e (two coalesced float4 sweeps) + batch-max (scaled domain)
  float lmax;
  {
    const float* sp = s2g + b * NC;
    float4 v0 = *(const float4*)(sp + t * 4);
    float4 v1 = *(const float4*)(sp + 1024 + t * 4);
    v0.x *= LOG2E; v0.y *= LOG2E; v0.z *= LOG2E; v0.w *= LOG2E;
    v1.x *= LOG2E; v1.y *= LOG2E; v1.z *= LOG2E; v1.w *= LOG2E;
    *(float4*)(s2_sh + t * 4) = v0;
    *(float4*)(s2_sh + 1024 + t * 4) = v1;
    lmax = fmaxf(fmaxf(fmaxf(v0.x, v0.y), fmaxf(v0.z, v0.w)),
                 fmaxf(fmaxf(v1.x, v1.y), fmaxf(v1.z, v1.w)));
#pragma unroll
    for (int off = 1; off < 64; off <<= 1)
      lmax = fmaxf(lmax, __shfl_xor(lmax, off));
    if (lane == 0) wmax_sh[wave] = lmax;
  }
  if (t < 16) s1_sh[t] = s1g[b * NC + i0 + t] * LOG2E;
  __syncthreads();

  const float s2max =
      fmaxf(fmaxf(wmax_sh[0], wmax_sh[1]), fmaxf(wmax_sh[2], wmax_sh[3]));

  const int m = lane & 15;   // A-frag row (query sub) and B-frag col (f sub)
  const int q = lane >> 4;
  const int gi = i0 + m;
  const float s1m = s1_sh[m];
  // upper bound of lrelu(s1m+s2j) in log2 domain, minus slack
  const float mm = fmaxf(s1m + s2max, 0.2f * (s1m + s2max)) - MOFF;
  const int* Ap = A + ((size_t)b * NC + gi) * NC;
  const unsigned short* whb = WhT + (size_t)b * NF * NC;

  // ones B-fragment: column 0 of tile = 1.0 -> accl col0 = row sums of P
  bf16x8_t onesf;
  {
    const __bf16 ov = (__bf16)((m == 0) ? 1.0f : 0.0f);
#pragma unroll
    for (int idx = 0; idx < 8; ++idx) onesf[idx] = ov;
  }

  floatx4_t acc[4], accl;
#pragma unroll
  for (int nt = 0; nt < 4; ++nt) acc[nt] = (floatx4_t){0.f, 0.f, 0.f, 0.f};
  accl = (floatx4_t){0.f, 0.f, 0.f, 0.f};

  // diagonal lives in the single K-tile kdiag for ALL 16 rows of this block
  const int kdiag = i0 >> 5;
  const int ktBeg = wave * 16, ktEnd = ktBeg + 16;
  const int* apb = Ap + q * 8;

#define BODY(KT, A0, A1)                                                      \
  {                                                                           \
    const int jq = (KT) * 32 + q * 8;                                         \
    ushort8_t bu0 = *(const ushort8_t*)(whb + (size_t)(0 * 16 + m) * NC + jq);\
    ushort8_t bu1 = *(const ushort8_t*)(whb + (size_t)(1 * 16 + m) * NC + jq);\
    ushort8_t bu2 = *(const ushort8_t*)(whb + (size_t)(2 * 16 + m) * NC + jq);\
    ushort8_t bu3 = *(const ushort8_t*)(whb + (size_t)(3 * 16 + m) * NC + jq);\
    float4 sA = *(const float4*)(s2_sh + jq);                                 \
    float4 sB = *(const float4*)(s2_sh + jq + 4);                             \
    const float sv[8] = {sA.x, sA.y, sA.z, sA.w, sB.x, sB.y, sB.z, sB.w};     \
    const int av[8] = {(A0).x, (A0).y, (A0).z, (A0).w,                        \
                       (A1).x, (A1).y, (A1).z, (A1).w};                       \
    float pm[8];                                                              \
    _Pragma("unroll")                                                         \
    for (int idx = 0; idx < 8; ++idx) {                                       \
      float x = s1m + sv[idx];                                                \
      float l = fmaxf(x - mm, __builtin_fmaf(0.2f, x, -mm));                  \
      pm[idx] = __builtin_amdgcn_exp2f(l);                                    \
    }                                                                         \
    if ((KT) == kdiag) {                                                      \
      _Pragma("unroll")                                                       \
      for (int idx = 0; idx < 8; ++idx)                                       \
        pm[idx] = ((av[idx] > 0) | (jq + idx == gi)) ? pm[idx] : 0.f;         \
    } else {                                                                  \
      _Pragma("unroll")                                                       \
      for (int idx = 0; idx < 8; ++idx)                                       \
        pm[idx] = (av[idx] > 0) ? pm[idx] : 0.f;                              \
    }                                                                         \
    bf16x8_t af;                                                              \
    _Pragma("unroll")                                                         \
    for (int idx = 0; idx < 8; ++idx) af[idx] = (__bf16)pm[idx];              \
    acc[0] = __builtin_amdgcn_mfma_f32_16x16x32_bf16(                         \
        af, __builtin_bit_cast(bf16x8_t, bu0), acc[0], 0, 0, 0);              \
    acc[1] = __builtin_amdgcn_mfma_f32_16x16x32_bf16(                         \
        af, __builtin_bit_cast(bf16x8_t, bu1), acc[1], 0, 0, 0);              \
    acc[2] = __builtin_amdgcn_mfma_f32_16x16x32_bf16(                         \
        af, __builtin_bit_cast(bf16x8_t, bu2), acc[2], 0, 0, 0);              \
    acc[3] = __builtin_amdgcn_mfma_f32_16x16x32_bf16(                         \
        af, __builtin_bit_cast(bf16x8_t, bu3), acc[3], 0, 0, 0);              \
    accl = __builtin_amdgcn_mfma_f32_16x16x32_bf16(af, onesf, accl, 0, 0, 0); \
  }

  // depth-2 A prefetch, unroll-by-2 with named register sets (no dyn indexing)
  int4 aA0 = *(const int4*)(apb + ktBeg * 32);
  int4 aA1 = *(const int4*)(apb + ktBeg * 32 + 4);
  int4 aB0 = *(const int4*)(apb + (ktBeg + 1) * 32);
  int4 aB1 = *(const int4*)(apb + (ktBeg + 1) * 32 + 4);

  for (int kt = ktBeg; kt < ktEnd; kt += 2) {
    {
      const int4 c0 = aA0, c1 = aA1;
      const int ktp = (kt + 2 < ktEnd) ? kt + 2 : ktEnd - 1;  // clamp: safe
      aA0 = *(const int4*)(apb + ktp * 32);
      aA1 = *(const int4*)(apb + ktp * 32 + 4);
      BODY(kt, c0, c1);
    }
    {
      const int4 c0 = aB0, c1 = aB1;
      const int ktp = (kt + 3 < ktEnd) ? kt + 3 : ktEnd - 1;  // clamp: safe
      aB0 = *(const int4*)(apb + ktp * 32);
      aB1 = *(const int4*)(apb + ktp * 32 + 4);
      BODY(kt + 1, c0, c1);
    }
  }
#undef BODY

  // cross-wave reduce: acc D[row=q*4+i2][col=m(+nt*16)], lsum from accl col 0
#pragma unroll
  for (int nt = 0; nt < 4; ++nt) {
#pragma unroll
    for (int i2 = 0; i2 < 4; ++i2) {
      red_sh[wave * (16 * RSTRIDE) + (q * 4 + i2) * RSTRIDE + nt * 16 + m] =
          acc[nt][i2];
    }
  }
  if (m == 0) {
#pragma unroll
    for (int i2 = 0; i2 < 4; ++i2)
      lsum_sh[wave * 16 + q * 4 + i2] = accl[i2];
  }
  __syncthreads();

  {
    const int row = t >> 4;
    const int f0 = (t & 15) * 4;
    float4 v = {0.f, 0.f, 0.f, 0.f};
    float ls = 0.f;
#pragma unroll
    for (int w = 0; w < 4; ++w) {
      const float* rp = red_sh + w * (16 * RSTRIDE) + row * RSTRIDE + f0;
      float4 vv = *(const float4*)rp;
      v.x += vv.x; v.y += vv.y; v.z += vv.z; v.w += vv.w;
      ls += lsum_sh[w * 16 + row];
    }
    const float inv = 1.0f / ls;
    float4 o;
    o.x = fmaxf(v.x * inv, 0.f);
    o.y = fmaxf(v.y * inv, 0.f);
    o.z = fmaxf(v.z * inv, 0.f);
    o.w = fmaxf(v.w * inv, 0.f);
    *(float4*)(out + (size_t)(b * NC + i0 + row) * NF + f0) = o;
  }
}

extern "C" void kernel_launch(void* const* d_in, const int* in_sizes, int n_in,
                              void* d_out, int out_size, void* d_ws, size_t ws_size,
                              hipStream_t stream) {
  const float* H = (const float*)d_in[0];
  const int* A = (const int*)d_in[1];
  const float* W = (const float*)d_in[2];
  const float* avec = (const float*)d_in[3];
  float* out = (float*)d_out;

  char* ws = (char*)d_ws;
  unsigned short* WhT = (unsigned short*)ws;                    // 2 MB
  float* s1 = (float*)(ws + (size_t)NB * NF * NC * 2);          // 64 KB
  float* s2 = s1 + NB * NC;                                     // 64 KB

  k1_prep<<<dim3(NB * (NC / 64)), dim3(256), 0, stream>>>(H, W, avec, s1, s2, WhT);
  k2_attn<<<dim3(NB * (NC / 16)), dim3(256), 0, stream>>>(A, s1, s2, WhT, out);
}